// Round 4
// baseline (399.979 us; speedup 1.0000x reference)
//
#include <hip/hip_runtime.h>

typedef __bf16 bf16x8 __attribute__((ext_vector_type(8)));
typedef __bf16 bf16x4 __attribute__((ext_vector_type(4)));
typedef float f32x4 __attribute__((ext_vector_type(4)));
typedef unsigned short u16;
typedef unsigned long long u64;

#define NX 8388608   // 8192*1024 elements (one [B*T, D] matrix)
#define NW 1048576   // 1024*1024 elements (one weight matrix)

__device__ __forceinline__ u16 f2bf(float f) {
  union { float f; unsigned u; } c; c.f = f;
  unsigned u = c.u;
  u += 0x7fffu + ((u >> 16) & 1u);   // round-to-nearest-even
  return (u16)(u >> 16);
}

__device__ __forceinline__ f32x4 mfma16(bf16x8 a, bf16x8 b, f32x4 c) {
  return __builtin_amdgcn_mfma_f32_16x16x32_bf16(a, b, c, 0, 0, 0);
}

// async global->LDS, 16 B per lane; LDS dest = uniform base + lane*16
__device__ __forceinline__ void gld16(void* lds, const void* g) {
  __builtin_amdgcn_global_load_lds(
      (const __attribute__((address_space(1))) unsigned int*)g,
      (__attribute__((address_space(3))) unsigned int*)lds, 16, 0, 0);
}

// ---------------------------------------------------------------------------
// Kernel 1: cast fp32 -> bf16 for q,k,v and the 4 weight matrices, with the
// mask bit-pack fused in (blocks >= 14336 do mask rows; one launch saved).
// ---------------------------------------------------------------------------
__global__ __launch_bounds__(256) void cast_all(
    const float* __restrict__ q, const float* __restrict__ k,
    const float* __restrict__ v, const float* __restrict__ wq,
    const float* __restrict__ wk, const float* __restrict__ wv,
    const float* __restrict__ wo, u16* __restrict__ xbf, u16* __restrict__ wbf,
    const int* __restrict__ mask, u64* __restrict__ bits) {
  if (blockIdx.x >= 14336) {
    // ---- mask pack: [B,T,T] int32 -> [B*T][32] u64 (bit=1: keep) ----
    const int row = (blockIdx.x - 14336) * 4 + (threadIdx.x >> 6);  // 0..8191
    const int lane = threadIdx.x & 63;
    const int* mrow = mask + (long long)row * 2048;
#pragma unroll
    for (int it = 0; it < 32; it++) {
      u64 w = __ballot(mrow[it * 64 + lane] != 0);
      if (lane == 0) bits[row * 32 + it] = w;
    }
    return;
  }
  long long i = ((long long)blockIdx.x * 256 + threadIdx.x) * 8;
  const float* src; u16* dst; long long off;
  if (i < (long long)NX)            { src = q; dst = xbf;            off = i; }
  else if (i < 2LL * NX)            { src = k; dst = xbf + NX;       off = i - NX; }
  else if (i < 3LL * NX)            { src = v; dst = xbf + 2LL * NX; off = i - 2LL * NX; }
  else {
    long long j = i - 3LL * NX;
    int w = (int)(j / NW); off = j - (long long)w * NW;
    src = (w == 0) ? wq : (w == 1) ? wk : (w == 2) ? wv : wo;
    dst = wbf + (long long)w * NW;
  }
  float4 a = *(const float4*)(src + off);
  float4 b = *(const float4*)(src + off + 4);
  u16 o[8] = {f2bf(a.x), f2bf(a.y), f2bf(a.z), f2bf(a.w),
              f2bf(b.x), f2bf(b.y), f2bf(b.z), f2bf(b.w)};
  *(uint4*)(dst + off) = *(const uint4*)o;
}

// ---------------------------------------------------------------------------
// Kernel 2/4: 128x128x(K=1024) NT-GEMM via global_load_lds + XOR swizzle.
// XCD-bijective block swizzle: XCD x owns m-panels [8x,8x+8) x all n (per z)
// -> per-XCD working set = A 2 MB + W 2 MB = 4 MB = one L2; 64 blocks =
// exactly one XCD's residency at 2 blocks/CU.
// MODE 0: QKV projection (z selects); Q (pre-scaled by log2e/8), K -> [B,H,T,64];
//         V -> [B,H,64,T]. All epilogues go through an LDS transpose so every
//         lane stores 128 B contiguous (no HBM write amplification).
// MODE 1: out projection -> fp32 [B*T,1024] + bias (two 32-col LDS passes).
// ---------------------------------------------------------------------------
template <int MODE>
__global__ __launch_bounds__(256, 2) void gemm128(
    const u16* __restrict__ Abase, const u16* __restrict__ Wbase,
    u16* __restrict__ oq, u16* __restrict__ ok, u16* __restrict__ ovt,
    const float* __restrict__ bias, float* __restrict__ of) {
  __shared__ alignas(16) u16 smem[2][128 * 64];
  u16* sA = smem[0];
  u16* sB = smem[1];
  const u16* A = Abase;
  const u16* W = Wbase;
  if (MODE == 0) { A += (long long)blockIdx.z * NX; W += (long long)blockIdx.z * NW; }
  const int tid = threadIdx.x, wave = tid >> 6, lane = tid & 63;
  const int quad = lane >> 4, l15 = lane & 15;
  // XCD-bijective swizzle over the 512 xy-blocks (x fastest in dispatch order;
  // 512 % 8 == 0 so the mapping holds identically for every z-slice).
  const int id = blockIdx.y * 8 + blockIdx.x;            // 0..511
  const int id2 = (id & 7) * 64 + (id >> 3);             // XCD-contiguous
  const int m0 = (id2 >> 3) * 128, n0 = (id2 & 7) * 128;
  const int wm = (wave & 1) * 64, wn = (wave >> 1) * 64;
  const int lr = lane >> 3;            // 0..7: row within 8-row staging group
  const int gc = (lane & 7) ^ lr;      // global 16B-chunk index for this lane
  f32x4 acc[4][4];
#pragma unroll
  for (int i = 0; i < 4; i++)
#pragma unroll
    for (int j = 0; j < 4; j++) acc[i][j] = (f32x4){0.f, 0.f, 0.f, 0.f};

  for (int ks = 0; ks < 16; ks++) {
    const int k0 = ks * 64;
    __syncthreads();   // previous iteration's frag reads complete
#pragma unroll
    for (int t = 0; t < 4; t++) {
      const int rb = wave * 32 + t * 8;        // wave-uniform row base
      gld16(&sA[rb * 64], &A[(m0 + rb + lr) * 1024 + k0 + gc * 8]);
      gld16(&sB[rb * 64], &W[(n0 + rb + lr) * 1024 + k0 + gc * 8]);
    }
    __syncthreads();   // staging complete (vmcnt drained at barrier)
#pragma unroll
    for (int kc = 0; kc < 2; kc++) {
      bf16x8 aF[4], bF[4];
#pragma unroll
      for (int i = 0; i < 4; i++)
        aF[i] = *(const bf16x8*)&sA[(wm + 16 * i + l15) * 64 +
                                    (((kc * 4 + quad) ^ (l15 & 7)) * 8)];
#pragma unroll
      for (int j = 0; j < 4; j++)
        bF[j] = *(const bf16x8*)&sB[(wn + 16 * j + l15) * 64 +
                                    (((kc * 4 + quad) ^ (l15 & 7)) * 8)];
#pragma unroll
      for (int i = 0; i < 4; i++)
#pragma unroll
        for (int j = 0; j < 4; j++) acc[i][j] = mfma16(aF[i], bF[j], acc[i][j]);
    }
  }

  // Epilogue. C/D layout: row = quad*4 + reg, col = l15 (m89/m91 verified).
  if (MODE == 0) {
    const int z = blockIdx.z;
    __syncthreads();                  // all waves done with sA/sB frag reads
    if (z < 2) {
      // Q/K: stage this wave's 64x64 chunk [t][d] in LDS (chunk-swizzled),
      // read back one 128-B row per lane -> fully coalesced stores.
      const float qscale = (z == 0) ? 0.18033688f : 1.0f;  // log2(e)/8 folded
      u16* dst = (z == 0) ? oq : ok;
      u16* sT = &smem[0][0] + wave * 4096;  // 64x64 u16 = 8 KB per wave
#pragma unroll
      for (int i = 0; i < 4; i++)
#pragma unroll
        for (int j = 0; j < 4; j++)
#pragma unroll
          for (int r = 0; r < 4; r++) {
            int m = 16 * i + quad * 4 + r;   // local t (0..63)
            int d = 16 * j + l15;            // local d (0..63)
            sT[m * 64 + (((d >> 3) ^ (m & 7)) * 8) + (d & 7)] =
                f2bf(acc[i][j][r] * qscale);
          }
      // wave-local read-back (in-order DS pipe; no barrier needed)
      const int bq = m0 >> 11, t0w = (m0 + wm) & 2047;
      const int hq = (n0 + wn) >> 6;   // d-range is 64-aligned
      u16* dq = dst + ((long long)((bq << 4) + hq) * 2048 + t0w + lane) * 64;
#pragma unroll
      for (int c = 0; c < 8; c++) {
        uint4 val = *(const uint4*)&sT[lane * 64 + ((c ^ (lane & 7)) * 8)];
        *(uint4*)(dq + c * 8) = val;
      }
    } else {
      // V^T: transpose each wave's 64x64 chunk in LDS, store coalesced.
      u16* sT = &smem[0][0] + wave * 4096;  // 64x64, chunk-swizzled
#pragma unroll
      for (int i = 0; i < 4; i++)
#pragma unroll
        for (int j = 0; j < 4; j++)
#pragma unroll
          for (int r = 0; r < 4; r++) {
            int m = 16 * i + quad * 4 + r;   // local t (0..63)
            int n = 16 * j + l15;            // local d (0..63)
            sT[n * 64 + (((m >> 3) ^ (n & 7)) * 8) + (m & 7)] = f2bf(acc[i][j][r]);
          }
      // wave-local read-back (in-order DS pipe; no barrier needed)
      const int b = m0 >> 11, t0 = (m0 + wm) & 2047;
      const int h = (n0 + wn) >> 6;   // d-range is 64-aligned
      u16* dst = ovt + ((long long)((b << 4) + h)) * 131072 + lane * 2048 + t0;
#pragma unroll
      for (int c = 0; c < 8; c++) {
        uint4 val = *(const uint4*)&sT[lane * 64 + ((c ^ (lane & 7)) * 8)];
        *(uint4*)(dst + c * 8) = val;
      }
    }
  } else {
    // fp32 out + bias: two 32-col LDS passes (8 KB/wave each), one 128-B
    // contiguous store region per lane per pass.
    float bb[4];
#pragma unroll
    for (int j = 0; j < 4; j++) bb[j] = bias[n0 + wn + 16 * j + l15];
    __syncthreads();                  // all waves done with sA/sB frag reads
    float* sW = (float*)&smem[0][0] + wave * 2048;   // 64x32 f32 = 8 KB
#pragma unroll
    for (int p = 0; p < 2; p++) {
#pragma unroll
      for (int i = 0; i < 4; i++)
#pragma unroll
        for (int jj = 0; jj < 2; jj++)
#pragma unroll
          for (int r = 0; r < 4; r++) {
            int m = 16 * i + quad * 4 + r;   // local row (0..63)
            int d = 16 * jj + l15;           // local col (0..31)
            sW[m * 32 + (((d >> 2) ^ (m & 7)) * 4) + (d & 3)] =
                acc[i][2 * p + jj][r] + bb[2 * p + jj];
          }
      float* dof = of + (long long)(m0 + wm + lane) * 1024 + n0 + wn + p * 32;
#pragma unroll
      for (int c = 0; c < 8; c++) {
        float4 val = *(const float4*)&sW[lane * 32 + ((c ^ (lane & 7)) * 4)];
        *(float4*)(dof + c * 4) = val;
      }
      // pass 1's ds_writes reuse the region after pass 0's ds_reads:
      // wave-local in-order DS pipe guarantees ordering.
    }
  }
}

// ---------------------------------------------------------------------------
// Kernel 3: flash attention, v4 — zero-shuffle P (no sP), 4 blocks/CU.
//   - Swapped QK^T: sacc = mfma(kF, qa) -> lane (quad,l15) holds q-row l15,
//     16 keys. K staged with A-frag-aligned key permutation
//       kap(c) = (c&32) + ((c>>2)&3)*8 + ((c&16)>>2) + (c&3)
//     so after exp the packed bf16 P IS the PV A-fragment. P never touches LDS.
//   - LDS 32 KB (sK/sV double-buffered only) -> 4 blocks/CU.
//   - Epilogue: LDS transpose (reuses sK after barrier) -> 128-B-contiguous
//     stores per lane (kills the 4.2x HBM write amplification seen in R3).
// ---------------------------------------------------------------------------
__device__ __forceinline__ void stage_tile(
    u16* sKb, u16* sVb, const u16* __restrict__ Kh, const u16* __restrict__ Vt,
    int bh, int kt, int wave, int lr8, int gc8) {
#pragma unroll
  for (int t = 0; t < 2; t++) {
    const int rb = wave * 16 + t * 8;          // wave-uniform row base (8 rows/1KB)
    const int c = rb + lr8;                    // LDS row this lane feeds
    // A-frag-aligned key permutation (see kernel header)
    const int kap = (c & 32) + (((c >> 2) & 3) << 3) + ((c & 16) >> 2) + (c & 3);
    gld16(&sKb[rb * 64], &Kh[(bh * 2048 + kt * 64 + kap) * 64 + gc8 * 8]);
    gld16(&sVb[rb * 64], &Vt[(bh * 64 + rb + lr8) * 2048 + kt * 64 + gc8 * 8]);
  }
}

__global__ __launch_bounds__(256, 4) void attn(
    const u16* __restrict__ Qh, const u16* __restrict__ Kh,
    const u16* __restrict__ Vt, const u64* __restrict__ mbits,
    u16* __restrict__ Zc) {
  __shared__ alignas(16) u16 sK[2][64 * 64];   // [perm key c][d], chunk swz ^(c&7)
  __shared__ alignas(16) u16 sV[2][64 * 64];   // [d][key],      chunk swz ^(d&7)
  const int tid = threadIdx.x, wave = tid >> 6, lane = tid & 63;
  const int quad = lane >> 4, l15 = lane & 15;
  // XCD-bijective swizzle: 1024 blocks; XCD x gets bh range [8x,8x+8), with
  // the 16 qt-blocks of each bh temporally adjacent (L2 locality).
  const int id = blockIdx.y * 16 + blockIdx.x;           // 0..1023
  const int id2 = (id & 7) * 128 + (id >> 3);
  const int bh = id2 >> 4, qt = id2 & 15;
  const int b = bh >> 4, h = bh & 15;
  const int q0 = qt * 128 + wave * 32;
  const int lr8 = lane >> 3, gc8 = (lane & 7) ^ lr8;

  bf16x8 qa[2][2];
#pragma unroll
  for (int g = 0; g < 2; g++)
#pragma unroll
    for (int kc = 0; kc < 2; kc++)
      qa[g][kc] = *(const bf16x8*)&Qh[(bh * 2048 + q0 + g * 16 + l15) * 64 +
                                      kc * 32 + quad * 8];

  // ---- prologue: full-mask check for this wave's 32 rows (all 2048 keys) ----
  const u64* mrow = mbits + (long long)(b * 2048 + q0) * 32;
  u64 am = ~0ull;
#pragma unroll
  for (int i = 0; i < 16; i++) am &= mrow[lane * 16 + i];
  const bool allfull = __all(am == ~0ull);

  f32x4 oacc[2][4];
#pragma unroll
  for (int g = 0; g < 2; g++)
#pragma unroll
    for (int j = 0; j < 4; j++) oacc[g][j] = (f32x4){0.f, 0.f, 0.f, 0.f};
  float lv[2] = {0.f, 0.f};

  // prime buffer 0 with tile 0
  stage_tile(&sK[0][0], &sV[0][0], Kh, Vt, bh, 0, wave, lr8, gc8);
  const f32x4 z4 = (f32x4){0.f, 0.f, 0.f, 0.f};

  for (int kt = 0; kt < 32; kt++) {
    const int cur = kt & 1;
    __syncthreads();   // tile kt staged (vmcnt drained); buf cur^1 free to refill
    if (kt < 31)
      stage_tile(&sK[cur ^ 1][0], &sV[cur ^ 1][0], Kh, Vt, bh, kt + 1,
                 wave, lr8, gc8);   // overlaps with this tile's compute

    // ---- S^T = K Q^T: 8 ds_read_b128 then 16 MFMA (swapped operands) ----
    bf16x8 kF[2][4];
#pragma unroll
    for (int kc = 0; kc < 2; kc++)
#pragma unroll
      for (int j = 0; j < 4; j++)
        kF[kc][j] = *(const bf16x8*)&sK[cur][(16 * j + l15) * 64 +
                                            (((kc * 4 + quad) ^ (l15 & 7)) * 8)];
    f32x4 sacc[2][4];
    __builtin_amdgcn_s_setprio(1);
#pragma unroll
    for (int j = 0; j < 4; j++)
#pragma unroll
      for (int g = 0; g < 2; g++) sacc[g][j] = mfma16(kF[0][j], qa[g][0], z4);
#pragma unroll
    for (int j = 0; j < 4; j++)
#pragma unroll
      for (int g = 0; g < 2; g++)
        sacc[g][j] = mfma16(kF[1][j], qa[g][1], sacc[g][j]);
    __builtin_amdgcn_s_setprio(0);

    // ---- p = exp2(s), packed straight into the PV A-fragment ----
    // sacc[g][j][r] = S[q-row g*16+l15][key 32*(j>>1) + 8*quad + 4*(j&1) + r]
    // pa[g][kc][e]  = P[q-row g*16+l15][key 32*kc + 8*quad + e]
    bf16x8 pa[2][2];
    if (allfull) {
#pragma unroll
      for (int g = 0; g < 2; g++) {
        float ls = 0.f;
#pragma unroll
        for (int kc = 0; kc < 2; kc++) {
          bf16x8 pk;
#pragma unroll
          for (int e = 0; e < 8; e++) {
            float p = __builtin_amdgcn_exp2f(sacc[g][2 * kc + (e >> 2)][e & 3]);
            ls += p;
            pk[e] = (__bf16)p;
          }
          pa[g][kc] = pk;
        }
        lv[g] += ls;
      }
    } else {
#pragma unroll
      for (int g = 0; g < 2; g++) {
        u64 w = mbits[(long long)(b * 2048 + q0 + g * 16 + l15) * 32 + kt];
        float ls = 0.f;
#pragma unroll
        for (int kc = 0; kc < 2; kc++) {
          bf16x8 pk;
#pragma unroll
          for (int e = 0; e < 8; e++) {
            float p = __builtin_amdgcn_exp2f(sacc[g][2 * kc + (e >> 2)][e & 3]);
            p = ((w >> (32 * kc + 8 * quad + e)) & 1ull) ? p : 0.f;
            ls += p;
            pk[e] = (__bf16)p;
          }
          pa[g][kc] = pk;
        }
        lv[g] += ls;
      }
    }

    // ---- O += P V: 8 vF reads + 16 MFMA (A-operand from registers) ----
    bf16x8 vF[2][4];
#pragma unroll
    for (int kc = 0; kc < 2; kc++)
#pragma unroll
      for (int j = 0; j < 4; j++)
        vF[kc][j] = *(const bf16x8*)&sV[cur][(16 * j + l15) * 64 +
                                             (((kc * 4 + quad) ^ (l15 & 7)) * 8)];
    __builtin_amdgcn_s_setprio(1);
#pragma unroll
    for (int kc = 0; kc < 2; kc++)
#pragma unroll
      for (int g = 0; g < 2; g++)
#pragma unroll
        for (int j = 0; j < 4; j++)
          oacc[g][j] = mfma16(pa[g][kc], vF[kc][j], oacc[g][j]);
    __builtin_amdgcn_s_setprio(0);
  }

  // ---- epilogue: row-sums, then LDS transpose -> coalesced 128-B stores ----
  float inv[2][4];
#pragma unroll
  for (int g = 0; g < 2; g++) {
    float s = lv[g];
    s += __shfl_xor(s, 16);
    s += __shfl_xor(s, 32);       // s = full row-sum for q-row g*16+l15
#pragma unroll
    for (int r = 0; r < 4; r++)
      inv[g][r] = 1.f / __shfl(s, quad * 4 + r);   // row-sum for oacc row quad*4+r
  }
  __syncthreads();                // all waves done with sK/sV tile reads
  u16* sT = &sK[0][0] + wave * 2048;   // 32x64 u16 = 4 KB per wave
#pragma unroll
  for (int g = 0; g < 2; g++)
#pragma unroll
    for (int j = 0; j < 4; j++)
#pragma unroll
      for (int r = 0; r < 4; r++) {
        int m = g * 16 + quad * 4 + r;   // local q-row (0..31)
        int d = 16 * j + l15;            // local col   (0..63)
        sT[m * 64 + (((d >> 3) ^ (m & 7)) * 8) + (d & 7)] =
            f2bf(oacc[g][j][r] * inv[g][r]);
      }
  // wave-local read-back: 2 lanes per row, 64 B contiguous per lane
  const int row = lane >> 1, half = lane & 1;
  u16* zdst = Zc + (long long)(b * 2048 + q0 + row) * 1024 + h * 64 + half * 32;
#pragma unroll
  for (int cc = 0; cc < 4; cc++) {
    uint4 val = *(const uint4*)&sT[row * 64 + (((half * 4 + cc) ^ (row & 7)) * 8)];
    *(uint4*)(zdst + cc * 8) = val;
  }
}

// ---------------------------------------------------------------------------
extern "C" void kernel_launch(void* const* d_in, const int* in_sizes, int n_in,
                              void* d_out, int out_size, void* d_ws, size_t ws_size,
                              hipStream_t stream) {
  (void)in_sizes; (void)n_in; (void)out_size; (void)ws_size;
  const float* q    = (const float*)d_in[0];
  const float* k    = (const float*)d_in[1];
  const float* v    = (const float*)d_in[2];
  const int*   mask = (const int*)d_in[3];
  const float* Wq   = (const float*)d_in[4];
  const float* Wk   = (const float*)d_in[5];
  const float* Wv   = (const float*)d_in[6];
  const float* Wo   = (const float*)d_in[7];
  const float* bo   = (const float*)d_in[8];
  float* out = (float*)d_out;

  u16* Xbf = (u16*)d_ws;             // 3 * NX
  u16* Wbf = Xbf + 3LL * NX;         // 4 * NW
  u16* Qh  = Wbf + 4LL * NW;         // [B,H,T,64]  (pre-scaled by log2e/8)
  u16* Kh  = Qh + (long long)NX;     // [B,H,T,64]
  u16* Vt  = Kh + (long long)NX;     // [B,H,64,T]
  u16* Zc  = Vt + (long long)NX;     // [B*T, 1024]
  u64* Mb  = (u64*)(Zc + (long long)NX);  // [B*T][32] packed mask bits (2 MB)

  cast_all<<<16384, 256, 0, stream>>>(q, k, v, Wq, Wk, Wv, Wo, Xbf, Wbf, mask, Mb);
  gemm128<0><<<dim3(8, 64, 3), 256, 0, stream>>>(Xbf, Wbf, Qh, Kh, Vt, nullptr, nullptr);
  attn<<<dim3(16, 64), 256, 0, stream>>>(Qh, Kh, Vt, Mb, Zc);
  gemm128<1><<<dim3(8, 64), 256, 0, stream>>>(Zc, Wbf + 3LL * NW, nullptr, nullptr, nullptr,
                                              bo, out);
}

// Round 5
// 396.551 us; speedup vs baseline: 1.0086x; 1.0086x over previous
//
#include <hip/hip_runtime.h>

typedef __bf16 bf16x8 __attribute__((ext_vector_type(8)));
typedef __bf16 bf16x4 __attribute__((ext_vector_type(4)));
typedef float f32x4 __attribute__((ext_vector_type(4)));
typedef unsigned short u16;
typedef unsigned long long u64;

#define NX 8388608   // 8192*1024 elements (one [B*T, D] matrix)
#define NW 1048576   // 1024*1024 elements (one weight matrix)

__device__ __forceinline__ u16 f2bf(float f) {
  union { float f; unsigned u; } c; c.f = f;
  unsigned u = c.u;
  u += 0x7fffu + ((u >> 16) & 1u);   // round-to-nearest-even
  return (u16)(u >> 16);
}

__device__ __forceinline__ f32x4 mfma16(bf16x8 a, bf16x8 b, f32x4 c) {
  return __builtin_amdgcn_mfma_f32_16x16x32_bf16(a, b, c, 0, 0, 0);
}

// async global->LDS, 16 B per lane; LDS dest = uniform base + lane*16
__device__ __forceinline__ void gld16(void* lds, const void* g) {
  __builtin_amdgcn_global_load_lds(
      (const __attribute__((address_space(1))) unsigned int*)g,
      (__attribute__((address_space(3))) unsigned int*)lds, 16, 0, 0);
}

// ---------------------------------------------------------------------------
// Kernel 1: cast fp32 -> bf16 for q,k,v and the 4 weight matrices, with the
// mask bit-pack fused in (blocks >= 14336 do mask rows; one launch saved).
// ---------------------------------------------------------------------------
__global__ __launch_bounds__(256) void cast_all(
    const float* __restrict__ q, const float* __restrict__ k,
    const float* __restrict__ v, const float* __restrict__ wq,
    const float* __restrict__ wk, const float* __restrict__ wv,
    const float* __restrict__ wo, u16* __restrict__ xbf, u16* __restrict__ wbf,
    const int* __restrict__ mask, u64* __restrict__ bits) {
  if (blockIdx.x >= 14336) {
    // ---- mask pack: [B,T,T] int32 -> [B*T][32] u64 (bit=1: keep) ----
    const int row = (blockIdx.x - 14336) * 4 + (threadIdx.x >> 6);  // 0..8191
    const int lane = threadIdx.x & 63;
    const int* mrow = mask + (long long)row * 2048;
#pragma unroll
    for (int it = 0; it < 32; it++) {
      u64 w = __ballot(mrow[it * 64 + lane] != 0);
      if (lane == 0) bits[row * 32 + it] = w;
    }
    return;
  }
  long long i = ((long long)blockIdx.x * 256 + threadIdx.x) * 8;
  const float* src; u16* dst; long long off;
  if (i < (long long)NX)            { src = q; dst = xbf;            off = i; }
  else if (i < 2LL * NX)            { src = k; dst = xbf + NX;       off = i - NX; }
  else if (i < 3LL * NX)            { src = v; dst = xbf + 2LL * NX; off = i - 2LL * NX; }
  else {
    long long j = i - 3LL * NX;
    int w = (int)(j / NW); off = j - (long long)w * NW;
    src = (w == 0) ? wq : (w == 1) ? wk : (w == 2) ? wv : wo;
    dst = wbf + (long long)w * NW;
  }
  float4 a = *(const float4*)(src + off);
  float4 b = *(const float4*)(src + off + 4);
  u16 o[8] = {f2bf(a.x), f2bf(a.y), f2bf(a.z), f2bf(a.w),
              f2bf(b.x), f2bf(b.y), f2bf(b.z), f2bf(b.w)};
  *(uint4*)(dst + off) = *(const uint4*)o;
}

// ---------------------------------------------------------------------------
// Kernel 2/4: 128x128x(K=1024) NT-GEMM via global_load_lds + XOR swizzle.
// __launch_bounds__(256,4): 4 blocks/CU (LDS 32 KB x4 = 128 <= 160 KB; VGPR
// cap 128 — acc 64 + frags 16 + addressing ~30 fits). The 2-barrier structure
// is latency-bound at 2 blocks/CU (proven on attn R2->R3); 4x wave diversity
// fills the barrier-drain bubbles, and the 1536-block grid now runs in 1.5
// dispatch rounds instead of 3.
// XCD-bijective block swizzle: XCD x owns m-panels [8x,8x+8) x all n (per z)
// -> per-XCD working set = A 2 MB + W 2 MB = 4 MB = one L2.
// MODE 0: QKV projection (z selects); Q (pre-scaled by log2e/8), K -> [B,H,T,64];
//         V -> [B,H,64,T]. Epilogues via LDS transpose -> 128 B/lane stores.
// MODE 1: out projection -> fp32 [B*T,1024] + bias (two 32-col LDS passes).
// ---------------------------------------------------------------------------
template <int MODE>
__global__ __launch_bounds__(256, 4) void gemm128(
    const u16* __restrict__ Abase, const u16* __restrict__ Wbase,
    u16* __restrict__ oq, u16* __restrict__ ok, u16* __restrict__ ovt,
    const float* __restrict__ bias, float* __restrict__ of) {
  __shared__ alignas(16) u16 smem[2][128 * 64];
  u16* sA = smem[0];
  u16* sB = smem[1];
  const u16* A = Abase;
  const u16* W = Wbase;
  if (MODE == 0) { A += (long long)blockIdx.z * NX; W += (long long)blockIdx.z * NW; }
  const int tid = threadIdx.x, wave = tid >> 6, lane = tid & 63;
  const int quad = lane >> 4, l15 = lane & 15;
  // XCD-bijective swizzle over the 512 xy-blocks (x fastest in dispatch order;
  // 512 % 8 == 0 so the mapping holds identically for every z-slice).
  const int id = blockIdx.y * 8 + blockIdx.x;            // 0..511
  const int id2 = (id & 7) * 64 + (id >> 3);             // XCD-contiguous
  const int m0 = (id2 >> 3) * 128, n0 = (id2 & 7) * 128;
  const int wm = (wave & 1) * 64, wn = (wave >> 1) * 64;
  const int lr = lane >> 3;            // 0..7: row within 8-row staging group
  const int gc = (lane & 7) ^ lr;      // global 16B-chunk index for this lane
  f32x4 acc[4][4];
#pragma unroll
  for (int i = 0; i < 4; i++)
#pragma unroll
    for (int j = 0; j < 4; j++) acc[i][j] = (f32x4){0.f, 0.f, 0.f, 0.f};

  for (int ks = 0; ks < 16; ks++) {
    const int k0 = ks * 64;
    __syncthreads();   // previous iteration's frag reads complete
#pragma unroll
    for (int t = 0; t < 4; t++) {
      const int rb = wave * 32 + t * 8;        // wave-uniform row base
      gld16(&sA[rb * 64], &A[(m0 + rb + lr) * 1024 + k0 + gc * 8]);
      gld16(&sB[rb * 64], &W[(n0 + rb + lr) * 1024 + k0 + gc * 8]);
    }
    __syncthreads();   // staging complete (vmcnt drained at barrier)
#pragma unroll
    for (int kc = 0; kc < 2; kc++) {
      bf16x8 aF[4], bF[4];
#pragma unroll
      for (int i = 0; i < 4; i++)
        aF[i] = *(const bf16x8*)&sA[(wm + 16 * i + l15) * 64 +
                                    (((kc * 4 + quad) ^ (l15 & 7)) * 8)];
#pragma unroll
      for (int j = 0; j < 4; j++)
        bF[j] = *(const bf16x8*)&sB[(wn + 16 * j + l15) * 64 +
                                    (((kc * 4 + quad) ^ (l15 & 7)) * 8)];
#pragma unroll
      for (int i = 0; i < 4; i++)
#pragma unroll
        for (int j = 0; j < 4; j++) acc[i][j] = mfma16(aF[i], bF[j], acc[i][j]);
    }
  }

  // Epilogue. C/D layout: row = quad*4 + reg, col = l15 (m89/m91 verified).
  if (MODE == 0) {
    const int z = blockIdx.z;
    __syncthreads();                  // all waves done with sA/sB frag reads
    if (z < 2) {
      // Q/K: stage this wave's 64x64 chunk [t][d] in LDS (chunk-swizzled),
      // read back one 128-B row per lane -> fully coalesced stores.
      const float qscale = (z == 0) ? 0.18033688f : 1.0f;  // log2(e)/8 folded
      u16* dst = (z == 0) ? oq : ok;
      u16* sT = &smem[0][0] + wave * 4096;  // 64x64 u16 = 8 KB per wave
#pragma unroll
      for (int i = 0; i < 4; i++)
#pragma unroll
        for (int j = 0; j < 4; j++)
#pragma unroll
          for (int r = 0; r < 4; r++) {
            int m = 16 * i + quad * 4 + r;   // local t (0..63)
            int d = 16 * j + l15;            // local d (0..63)
            sT[m * 64 + (((d >> 3) ^ (m & 7)) * 8) + (d & 7)] =
                f2bf(acc[i][j][r] * qscale);
          }
      // wave-local read-back (in-order DS pipe; no barrier needed)
      const int bq = m0 >> 11, t0w = (m0 + wm) & 2047;
      const int hq = (n0 + wn) >> 6;   // d-range is 64-aligned
      u16* dq = dst + ((long long)((bq << 4) + hq) * 2048 + t0w + lane) * 64;
#pragma unroll
      for (int c = 0; c < 8; c++) {
        uint4 val = *(const uint4*)&sT[lane * 64 + ((c ^ (lane & 7)) * 8)];
        *(uint4*)(dq + c * 8) = val;
      }
    } else {
      // V^T: transpose each wave's 64x64 chunk in LDS, store coalesced.
      u16* sT = &smem[0][0] + wave * 4096;  // 64x64, chunk-swizzled
#pragma unroll
      for (int i = 0; i < 4; i++)
#pragma unroll
        for (int j = 0; j < 4; j++)
#pragma unroll
          for (int r = 0; r < 4; r++) {
            int m = 16 * i + quad * 4 + r;   // local t (0..63)
            int n = 16 * j + l15;            // local d (0..63)
            sT[n * 64 + (((m >> 3) ^ (n & 7)) * 8) + (m & 7)] = f2bf(acc[i][j][r]);
          }
      // wave-local read-back (in-order DS pipe; no barrier needed)
      const int b = m0 >> 11, t0 = (m0 + wm) & 2047;
      const int h = (n0 + wn) >> 6;   // d-range is 64-aligned
      u16* dst = ovt + ((long long)((b << 4) + h)) * 131072 + lane * 2048 + t0;
#pragma unroll
      for (int c = 0; c < 8; c++) {
        uint4 val = *(const uint4*)&sT[lane * 64 + ((c ^ (lane & 7)) * 8)];
        *(uint4*)(dst + c * 8) = val;
      }
    }
  } else {
    // fp32 out + bias: two 32-col LDS passes (8 KB/wave each), one 128-B
    // contiguous store region per lane per pass.
    float bb[4];
#pragma unroll
    for (int j = 0; j < 4; j++) bb[j] = bias[n0 + wn + 16 * j + l15];
    __syncthreads();                  // all waves done with sA/sB frag reads
    float* sW = (float*)&smem[0][0] + wave * 2048;   // 64x32 f32 = 8 KB
#pragma unroll
    for (int p = 0; p < 2; p++) {
#pragma unroll
      for (int i = 0; i < 4; i++)
#pragma unroll
        for (int jj = 0; jj < 2; jj++)
#pragma unroll
          for (int r = 0; r < 4; r++) {
            int m = 16 * i + quad * 4 + r;   // local row (0..63)
            int d = 16 * jj + l15;           // local col (0..31)
            sW[m * 32 + (((d >> 2) ^ (m & 7)) * 4) + (d & 3)] =
                acc[i][2 * p + jj][r] + bb[2 * p + jj];
          }
      float* dof = of + (long long)(m0 + wm + lane) * 1024 + n0 + wn + p * 32;
#pragma unroll
      for (int c = 0; c < 8; c++) {
        float4 val = *(const float4*)&sW[lane * 32 + ((c ^ (lane & 7)) * 4)];
        *(float4*)(dof + c * 4) = val;
      }
      // pass 1's ds_writes reuse the region after pass 0's ds_reads:
      // wave-local in-order DS pipe guarantees ordering.
    }
  }
}

// ---------------------------------------------------------------------------
// Kernel 3: flash attention, v4 (R3 form — direct-store epilogue restored).
//   - Swapped QK^T: sacc = mfma(kF, qa) -> lane (quad,l15) holds q-row l15,
//     16 keys. K staged with A-frag-aligned key permutation
//       kap(c) = (c&32) + ((c>>2)&3)*8 + ((c&16)>>2) + (c&3)
//     so after exp the packed bf16 P IS the PV A-fragment. P never touches LDS.
//   - LDS 32 KB (sK/sV double-buffered only) -> 4 blocks/CU.
//   - Direct strided stores in the epilogue: R4's LDS-transpose epilogue cost
//     6 us (extra barrier + DS round-trip); WRITE_SIZE is dominated by L2
//     writeback of gemm<0>'s output, not store amplification. Reverted.
// ---------------------------------------------------------------------------
__device__ __forceinline__ void stage_tile(
    u16* sKb, u16* sVb, const u16* __restrict__ Kh, const u16* __restrict__ Vt,
    int bh, int kt, int wave, int lr8, int gc8) {
#pragma unroll
  for (int t = 0; t < 2; t++) {
    const int rb = wave * 16 + t * 8;          // wave-uniform row base (8 rows/1KB)
    const int c = rb + lr8;                    // LDS row this lane feeds
    // A-frag-aligned key permutation (see kernel header)
    const int kap = (c & 32) + (((c >> 2) & 3) << 3) + ((c & 16) >> 2) + (c & 3);
    gld16(&sKb[rb * 64], &Kh[(bh * 2048 + kt * 64 + kap) * 64 + gc8 * 8]);
    gld16(&sVb[rb * 64], &Vt[(bh * 64 + rb + lr8) * 2048 + kt * 64 + gc8 * 8]);
  }
}

__global__ __launch_bounds__(256, 4) void attn(
    const u16* __restrict__ Qh, const u16* __restrict__ Kh,
    const u16* __restrict__ Vt, const u64* __restrict__ mbits,
    u16* __restrict__ Zc) {
  __shared__ alignas(16) u16 sK[2][64 * 64];   // [perm key c][d], chunk swz ^(c&7)
  __shared__ alignas(16) u16 sV[2][64 * 64];   // [d][key],      chunk swz ^(d&7)
  const int tid = threadIdx.x, wave = tid >> 6, lane = tid & 63;
  const int quad = lane >> 4, l15 = lane & 15;
  // XCD-bijective swizzle: 1024 blocks; XCD x gets bh range [8x,8x+8), with
  // the 16 qt-blocks of each bh temporally adjacent (L2 locality).
  const int id = blockIdx.y * 16 + blockIdx.x;           // 0..1023
  const int id2 = (id & 7) * 128 + (id >> 3);
  const int bh = id2 >> 4, qt = id2 & 15;
  const int b = bh >> 4, h = bh & 15;
  const int q0 = qt * 128 + wave * 32;
  const int lr8 = lane >> 3, gc8 = (lane & 7) ^ lr8;

  bf16x8 qa[2][2];
#pragma unroll
  for (int g = 0; g < 2; g++)
#pragma unroll
    for (int kc = 0; kc < 2; kc++)
      qa[g][kc] = *(const bf16x8*)&Qh[(bh * 2048 + q0 + g * 16 + l15) * 64 +
                                      kc * 32 + quad * 8];

  // ---- prologue: full-mask check for this wave's 32 rows (all 2048 keys) ----
  const u64* mrow = mbits + (long long)(b * 2048 + q0) * 32;
  u64 am = ~0ull;
#pragma unroll
  for (int i = 0; i < 16; i++) am &= mrow[lane * 16 + i];
  const bool allfull = __all(am == ~0ull);

  f32x4 oacc[2][4];
#pragma unroll
  for (int g = 0; g < 2; g++)
#pragma unroll
    for (int j = 0; j < 4; j++) oacc[g][j] = (f32x4){0.f, 0.f, 0.f, 0.f};
  float lv[2] = {0.f, 0.f};

  // prime buffer 0 with tile 0
  stage_tile(&sK[0][0], &sV[0][0], Kh, Vt, bh, 0, wave, lr8, gc8);
  const f32x4 z4 = (f32x4){0.f, 0.f, 0.f, 0.f};

  for (int kt = 0; kt < 32; kt++) {
    const int cur = kt & 1;
    __syncthreads();   // tile kt staged (vmcnt drained); buf cur^1 free to refill
    if (kt < 31)
      stage_tile(&sK[cur ^ 1][0], &sV[cur ^ 1][0], Kh, Vt, bh, kt + 1,
                 wave, lr8, gc8);   // overlaps with this tile's compute

    // ---- S^T = K Q^T: 8 ds_read_b128 then 16 MFMA (swapped operands) ----
    bf16x8 kF[2][4];
#pragma unroll
    for (int kc = 0; kc < 2; kc++)
#pragma unroll
      for (int j = 0; j < 4; j++)
        kF[kc][j] = *(const bf16x8*)&sK[cur][(16 * j + l15) * 64 +
                                            (((kc * 4 + quad) ^ (l15 & 7)) * 8)];
    f32x4 sacc[2][4];
    __builtin_amdgcn_s_setprio(1);
#pragma unroll
    for (int j = 0; j < 4; j++)
#pragma unroll
      for (int g = 0; g < 2; g++) sacc[g][j] = mfma16(kF[0][j], qa[g][0], z4);
#pragma unroll
    for (int j = 0; j < 4; j++)
#pragma unroll
      for (int g = 0; g < 2; g++)
        sacc[g][j] = mfma16(kF[1][j], qa[g][1], sacc[g][j]);
    __builtin_amdgcn_s_setprio(0);

    // ---- p = exp2(s), packed straight into the PV A-fragment ----
    // sacc[g][j][r] = S[q-row g*16+l15][key 32*(j>>1) + 8*quad + 4*(j&1) + r]
    // pa[g][kc][e]  = P[q-row g*16+l15][key 32*kc + 8*quad + e]
    bf16x8 pa[2][2];
    if (allfull) {
#pragma unroll
      for (int g = 0; g < 2; g++) {
        float ls = 0.f;
#pragma unroll
        for (int kc = 0; kc < 2; kc++) {
          bf16x8 pk;
#pragma unroll
          for (int e = 0; e < 8; e++) {
            float p = __builtin_amdgcn_exp2f(sacc[g][2 * kc + (e >> 2)][e & 3]);
            ls += p;
            pk[e] = (__bf16)p;
          }
          pa[g][kc] = pk;
        }
        lv[g] += ls;
      }
    } else {
#pragma unroll
      for (int g = 0; g < 2; g++) {
        u64 w = mbits[(long long)(b * 2048 + q0 + g * 16 + l15) * 32 + kt];
        float ls = 0.f;
#pragma unroll
        for (int kc = 0; kc < 2; kc++) {
          bf16x8 pk;
#pragma unroll
          for (int e = 0; e < 8; e++) {
            float p = __builtin_amdgcn_exp2f(sacc[g][2 * kc + (e >> 2)][e & 3]);
            p = ((w >> (32 * kc + 8 * quad + e)) & 1ull) ? p : 0.f;
            ls += p;
            pk[e] = (__bf16)p;
          }
          pa[g][kc] = pk;
        }
        lv[g] += ls;
      }
    }

    // ---- O += P V: 8 vF reads + 16 MFMA (A-operand from registers) ----
    bf16x8 vF[2][4];
#pragma unroll
    for (int kc = 0; kc < 2; kc++)
#pragma unroll
      for (int j = 0; j < 4; j++)
        vF[kc][j] = *(const bf16x8*)&sV[cur][(16 * j + l15) * 64 +
                                             (((kc * 4 + quad) ^ (l15 & 7)) * 8)];
    __builtin_amdgcn_s_setprio(1);
#pragma unroll
    for (int kc = 0; kc < 2; kc++)
#pragma unroll
      for (int g = 0; g < 2; g++)
#pragma unroll
        for (int j = 0; j < 4; j++)
          oacc[g][j] = mfma16(pa[g][kc], vF[kc][j], oacc[g][j]);
    __builtin_amdgcn_s_setprio(0);
  }

  // ---- epilogue: row-sums via cross-quad reduce, then scale + store ----
#pragma unroll
  for (int g = 0; g < 2; g++) {
    float s = lv[g];
    s += __shfl_xor(s, 16);
    s += __shfl_xor(s, 32);       // s = full row-sum for q-row g*16+l15
    float inv[4];
#pragma unroll
    for (int r = 0; r < 4; r++)
      inv[r] = 1.f / __shfl(s, quad * 4 + r);   // row-sum for oacc row quad*4+r
#pragma unroll
    for (int j = 0; j < 4; j++)
#pragma unroll
      for (int r = 0; r < 4; r++) {
        int t = q0 + g * 16 + quad * 4 + r;
        Zc[(b * 2048 + t) * 1024 + h * 64 + 16 * j + l15] =
            f2bf(oacc[g][j][r] * inv[r]);
      }
  }
}

// ---------------------------------------------------------------------------
extern "C" void kernel_launch(void* const* d_in, const int* in_sizes, int n_in,
                              void* d_out, int out_size, void* d_ws, size_t ws_size,
                              hipStream_t stream) {
  (void)in_sizes; (void)n_in; (void)out_size; (void)ws_size;
  const float* q    = (const float*)d_in[0];
  const float* k    = (const float*)d_in[1];
  const float* v    = (const float*)d_in[2];
  const int*   mask = (const int*)d_in[3];
  const float* Wq   = (const float*)d_in[4];
  const float* Wk   = (const float*)d_in[5];
  const float* Wv   = (const float*)d_in[6];
  const float* Wo   = (const float*)d_in[7];
  const float* bo   = (const float*)d_in[8];
  float* out = (float*)d_out;

  u16* Xbf = (u16*)d_ws;             // 3 * NX
  u16* Wbf = Xbf + 3LL * NX;         // 4 * NW
  u16* Qh  = Wbf + 4LL * NW;         // [B,H,T,64]  (pre-scaled by log2e/8)
  u16* Kh  = Qh + (long long)NX;     // [B,H,T,64]
  u16* Vt  = Kh + (long long)NX;     // [B,H,64,T]
  u16* Zc  = Vt + (long long)NX;     // [B*T, 1024]
  u64* Mb  = (u64*)(Zc + (long long)NX);  // [B*T][32] packed mask bits (2 MB)

  cast_all<<<16384, 256, 0, stream>>>(q, k, v, Wq, Wk, Wv, Wo, Xbf, Wbf, mask, Mb);
  gemm128<0><<<dim3(8, 64, 3), 256, 0, stream>>>(Xbf, Wbf, Qh, Kh, Vt, nullptr, nullptr);
  attn<<<dim3(16, 64), 256, 0, stream>>>(Qh, Kh, Vt, Mb, Zc);
  gemm128<1><<<dim3(8, 64), 256, 0, stream>>>(Zc, Wbf + 3LL * NW, nullptr, nullptr, nullptr,
                                              bo, out);
}

// Round 6
// 390.100 us; speedup vs baseline: 1.0253x; 1.0165x over previous
//
#include <hip/hip_runtime.h>

typedef __bf16 bf16x8 __attribute__((ext_vector_type(8)));
typedef __bf16 bf16x4 __attribute__((ext_vector_type(4)));
typedef float f32x4 __attribute__((ext_vector_type(4)));
typedef unsigned short u16;
typedef unsigned long long u64;

#define NX 8388608   // 8192*1024 elements (one [B*T, D] matrix)
#define NW 1048576   // 1024*1024 elements (one weight matrix)

__device__ __forceinline__ u16 f2bf(float f) {
  union { float f; unsigned u; } c; c.f = f;
  unsigned u = c.u;
  u += 0x7fffu + ((u >> 16) & 1u);   // round-to-nearest-even
  return (u16)(u >> 16);
}

__device__ __forceinline__ f32x4 mfma16(bf16x8 a, bf16x8 b, f32x4 c) {
  return __builtin_amdgcn_mfma_f32_16x16x32_bf16(a, b, c, 0, 0, 0);
}

// async global->LDS, 16 B per lane; LDS dest = uniform base + lane*16
__device__ __forceinline__ void gld16(void* lds, const void* g) {
  __builtin_amdgcn_global_load_lds(
      (const __attribute__((address_space(1))) unsigned int*)g,
      (__attribute__((address_space(3))) unsigned int*)lds, 16, 0, 0);
}

// ---------------------------------------------------------------------------
// Kernel 1: cast fp32 -> bf16 for q,k,v and the 4 weight matrices, with the
// mask bit-pack fused in (blocks >= 14336 do mask rows; one launch saved).
// ---------------------------------------------------------------------------
__global__ __launch_bounds__(256) void cast_all(
    const float* __restrict__ q, const float* __restrict__ k,
    const float* __restrict__ v, const float* __restrict__ wq,
    const float* __restrict__ wk, const float* __restrict__ wv,
    const float* __restrict__ wo, u16* __restrict__ xbf, u16* __restrict__ wbf,
    const int* __restrict__ mask, u64* __restrict__ bits) {
  if (blockIdx.x >= 14336) {
    // ---- mask pack: [B,T,T] int32 -> [B*T][32] u64 (bit=1: keep) ----
    const int row = (blockIdx.x - 14336) * 4 + (threadIdx.x >> 6);  // 0..8191
    const int lane = threadIdx.x & 63;
    const int* mrow = mask + (long long)row * 2048;
#pragma unroll
    for (int it = 0; it < 32; it++) {
      u64 w = __ballot(mrow[it * 64 + lane] != 0);
      if (lane == 0) bits[row * 32 + it] = w;
    }
    return;
  }
  long long i = ((long long)blockIdx.x * 256 + threadIdx.x) * 8;
  const float* src; u16* dst; long long off;
  if (i < (long long)NX)            { src = q; dst = xbf;            off = i; }
  else if (i < 2LL * NX)            { src = k; dst = xbf + NX;       off = i - NX; }
  else if (i < 3LL * NX)            { src = v; dst = xbf + 2LL * NX; off = i - 2LL * NX; }
  else {
    long long j = i - 3LL * NX;
    int w = (int)(j / NW); off = j - (long long)w * NW;
    src = (w == 0) ? wq : (w == 1) ? wk : (w == 2) ? wv : wo;
    dst = wbf + (long long)w * NW;
  }
  float4 a = *(const float4*)(src + off);
  float4 b = *(const float4*)(src + off + 4);
  u16 o[8] = {f2bf(a.x), f2bf(a.y), f2bf(a.z), f2bf(a.w),
              f2bf(b.x), f2bf(b.y), f2bf(b.z), f2bf(b.w)};
  *(uint4*)(dst + off) = *(const uint4*)o;
}

// ---------------------------------------------------------------------------
// Kernel 2/4: 128x128x(K=1024) NT-GEMM, counted-vmcnt double-buffered K-loop.
//   Old structure: __syncthreads() drains vmcnt(0) at every K-step -> all
//   waves eat full load latency 16x/block (the documented m97-structure
//   stall). New: stage tile ks+1 into buf^1 BEFORE computing tile ks; wait
//   only s_waitcnt vmcnt(8) (tile ks's own 8 loads, issued one full K-step
//   earlier -> already landed) + raw s_barrier (no drain). sched_barrier(0)
//   pins compute between the barriers (rule #18 hoist hazard).
//   LDS 64 KB (2 x 32 KB stage) -> 2 blocks/CU.
// XCD-bijective block swizzle: XCD x owns m-panels [8x,8x+8) x all n (per z)
// -> per-XCD working set = A 2 MB + W 2 MB = 4 MB = one L2.
// MODE 0: QKV projection (z selects); Q (pre-scaled by log2e/8), K -> [B,H,T,64];
//         V -> [B,H,64,T]. Epilogues via LDS transpose -> 128 B/lane stores.
// MODE 1: out projection -> fp32 [B*T,1024] + bias (two 32-col LDS passes).
// ---------------------------------------------------------------------------
__device__ __forceinline__ void gstage(
    u16* sAb, u16* sBb, const u16* __restrict__ A, const u16* __restrict__ W,
    int m0, int n0, int k0, int wave, int lr, int gc) {
#pragma unroll
  for (int t = 0; t < 4; t++) {
    const int rb = wave * 32 + t * 8;          // wave-uniform row base
    gld16(&sAb[rb * 64], &A[(m0 + rb + lr) * 1024 + k0 + gc * 8]);
    gld16(&sBb[rb * 64], &W[(n0 + rb + lr) * 1024 + k0 + gc * 8]);
  }
}

template <int MODE>
__global__ __launch_bounds__(256, 2) void gemm128(
    const u16* __restrict__ Abase, const u16* __restrict__ Wbase,
    u16* __restrict__ oq, u16* __restrict__ ok, u16* __restrict__ ovt,
    const float* __restrict__ bias, float* __restrict__ of) {
  __shared__ alignas(16) u16 smem[2][2][128 * 64];   // [buf][A/B][tile]
  const u16* A = Abase;
  const u16* W = Wbase;
  if (MODE == 0) { A += (long long)blockIdx.z * NX; W += (long long)blockIdx.z * NW; }
  const int tid = threadIdx.x, wave = tid >> 6, lane = tid & 63;
  const int quad = lane >> 4, l15 = lane & 15;
  // XCD-bijective swizzle over the 512 xy-blocks (x fastest in dispatch order;
  // 512 % 8 == 0 so the mapping holds identically for every z-slice).
  const int id = blockIdx.y * 8 + blockIdx.x;            // 0..511
  const int id2 = (id & 7) * 64 + (id >> 3);             // XCD-contiguous
  const int m0 = (id2 >> 3) * 128, n0 = (id2 & 7) * 128;
  const int wm = (wave & 1) * 64, wn = (wave >> 1) * 64;
  const int lr = lane >> 3;            // 0..7: row within 8-row staging group
  const int gc = (lane & 7) ^ lr;      // global 16B-chunk index for this lane
  f32x4 acc[4][4];
#pragma unroll
  for (int i = 0; i < 4; i++)
#pragma unroll
    for (int j = 0; j < 4; j++) acc[i][j] = (f32x4){0.f, 0.f, 0.f, 0.f};

  // prime buffer 0 with K-tile 0
  gstage(smem[0][0], smem[0][1], A, W, m0, n0, 0, wave, lr, gc);
  int buf = 0;
  for (int ks = 0; ks < 16; ks++) {
    if (ks < 15) {
      // prefetch next K-tile into the other buffer (8 loads in flight across
      // this tile's compute)
      gstage(smem[buf ^ 1][0], smem[buf ^ 1][1], A, W, m0, n0, (ks + 1) * 64,
             wave, lr, gc);
      asm volatile("s_waitcnt vmcnt(8)" ::: "memory");   // tile ks staged
    } else {
      asm volatile("s_waitcnt vmcnt(0)" ::: "memory");   // last tile staged
    }
    __builtin_amdgcn_s_barrier();          // all waves: tile ks visible
    __builtin_amdgcn_sched_barrier(0);     // no ds_read hoists above this
    const u16* cA = smem[buf][0];
    const u16* cB = smem[buf][1];
#pragma unroll
    for (int kc = 0; kc < 2; kc++) {
      bf16x8 aF[4], bF[4];
#pragma unroll
      for (int i = 0; i < 4; i++)
        aF[i] = *(const bf16x8*)&cA[(wm + 16 * i + l15) * 64 +
                                    (((kc * 4 + quad) ^ (l15 & 7)) * 8)];
#pragma unroll
      for (int j = 0; j < 4; j++)
        bF[j] = *(const bf16x8*)&cB[(wn + 16 * j + l15) * 64 +
                                    (((kc * 4 + quad) ^ (l15 & 7)) * 8)];
#pragma unroll
      for (int i = 0; i < 4; i++)
#pragma unroll
        for (int j = 0; j < 4; j++) acc[i][j] = mfma16(aF[i], bF[j], acc[i][j]);
    }
    __builtin_amdgcn_sched_barrier(0);     // no compute sinks below this
    __builtin_amdgcn_s_barrier();          // all waves done reading buf
    buf ^= 1;
  }

  // Epilogue. C/D layout: row = quad*4 + reg, col = l15 (m89/m91 verified).
  if (MODE == 0) {
    const int z = blockIdx.z;
    __syncthreads();                  // all waves past final compute barrier
    if (z < 2) {
      // Q/K: stage this wave's 64x64 chunk [t][d] in LDS (chunk-swizzled),
      // read back one 128-B row per lane -> fully coalesced stores.
      const float qscale = (z == 0) ? 0.18033688f : 1.0f;  // log2(e)/8 folded
      u16* dst = (z == 0) ? oq : ok;
      u16* sT = &smem[0][0][0] + wave * 4096;  // 64x64 u16 = 8 KB per wave
#pragma unroll
      for (int i = 0; i < 4; i++)
#pragma unroll
        for (int j = 0; j < 4; j++)
#pragma unroll
          for (int r = 0; r < 4; r++) {
            int m = 16 * i + quad * 4 + r;   // local t (0..63)
            int d = 16 * j + l15;            // local d (0..63)
            sT[m * 64 + (((d >> 3) ^ (m & 7)) * 8) + (d & 7)] =
                f2bf(acc[i][j][r] * qscale);
          }
      // wave-local read-back (in-order DS pipe; no barrier needed)
      const int bq = m0 >> 11, t0w = (m0 + wm) & 2047;
      const int hq = (n0 + wn) >> 6;   // d-range is 64-aligned
      u16* dq = dst + ((long long)((bq << 4) + hq) * 2048 + t0w + lane) * 64;
#pragma unroll
      for (int c = 0; c < 8; c++) {
        uint4 val = *(const uint4*)&sT[lane * 64 + ((c ^ (lane & 7)) * 8)];
        *(uint4*)(dq + c * 8) = val;
      }
    } else {
      // V^T: transpose each wave's 64x64 chunk in LDS, store coalesced.
      u16* sT = &smem[0][0][0] + wave * 4096;  // 64x64, chunk-swizzled
#pragma unroll
      for (int i = 0; i < 4; i++)
#pragma unroll
        for (int j = 0; j < 4; j++)
#pragma unroll
          for (int r = 0; r < 4; r++) {
            int m = 16 * i + quad * 4 + r;   // local t (0..63)
            int n = 16 * j + l15;            // local d (0..63)
            sT[n * 64 + (((m >> 3) ^ (n & 7)) * 8) + (m & 7)] = f2bf(acc[i][j][r]);
          }
      // wave-local read-back (in-order DS pipe; no barrier needed)
      const int b = m0 >> 11, t0 = (m0 + wm) & 2047;
      const int h = (n0 + wn) >> 6;   // d-range is 64-aligned
      u16* dst = ovt + ((long long)((b << 4) + h)) * 131072 + lane * 2048 + t0;
#pragma unroll
      for (int c = 0; c < 8; c++) {
        uint4 val = *(const uint4*)&sT[lane * 64 + ((c ^ (lane & 7)) * 8)];
        *(uint4*)(dst + c * 8) = val;
      }
    }
  } else {
    // fp32 out + bias: two 32-col LDS passes (8 KB/wave each), one 128-B
    // contiguous store region per lane per pass.
    float bb[4];
#pragma unroll
    for (int j = 0; j < 4; j++) bb[j] = bias[n0 + wn + 16 * j + l15];
    __syncthreads();                  // all waves past final compute barrier
    float* sW = (float*)&smem[0][0][0] + wave * 2048;   // 64x32 f32 = 8 KB
#pragma unroll
    for (int p = 0; p < 2; p++) {
#pragma unroll
      for (int i = 0; i < 4; i++)
#pragma unroll
        for (int jj = 0; jj < 2; jj++)
#pragma unroll
          for (int r = 0; r < 4; r++) {
            int m = 16 * i + quad * 4 + r;   // local row (0..63)
            int d = 16 * jj + l15;           // local col (0..31)
            sW[m * 32 + (((d >> 2) ^ (m & 7)) * 4) + (d & 3)] =
                acc[i][2 * p + jj][r] + bb[2 * p + jj];
          }
      float* dof = of + (long long)(m0 + wm + lane) * 1024 + n0 + wn + p * 32;
#pragma unroll
      for (int c = 0; c < 8; c++) {
        float4 val = *(const float4*)&sW[lane * 32 + ((c ^ (lane & 7)) * 4)];
        *(float4*)(dof + c * 4) = val;
      }
      // pass 1's ds_writes reuse the region after pass 0's ds_reads:
      // wave-local in-order DS pipe guarantees ordering.
    }
  }
}

// ---------------------------------------------------------------------------
// Kernel 3: flash attention, v4 (R3 form — direct-store epilogue; 90.1 us).
//   - Swapped QK^T: sacc = mfma(kF, qa) -> lane (quad,l15) holds q-row l15,
//     16 keys. K staged with A-frag-aligned key permutation
//       kap(c) = (c&32) + ((c>>2)&3)*8 + ((c&16)>>2) + (c&3)
//     so after exp the packed bf16 P IS the PV A-fragment. P never touches LDS.
//   - LDS 32 KB (sK/sV double-buffered only) -> 4 blocks/CU.
// ---------------------------------------------------------------------------
__device__ __forceinline__ void stage_tile(
    u16* sKb, u16* sVb, const u16* __restrict__ Kh, const u16* __restrict__ Vt,
    int bh, int kt, int wave, int lr8, int gc8) {
#pragma unroll
  for (int t = 0; t < 2; t++) {
    const int rb = wave * 16 + t * 8;          // wave-uniform row base (8 rows/1KB)
    const int c = rb + lr8;                    // LDS row this lane feeds
    // A-frag-aligned key permutation (see kernel header)
    const int kap = (c & 32) + (((c >> 2) & 3) << 3) + ((c & 16) >> 2) + (c & 3);
    gld16(&sKb[rb * 64], &Kh[(bh * 2048 + kt * 64 + kap) * 64 + gc8 * 8]);
    gld16(&sVb[rb * 64], &Vt[(bh * 64 + rb + lr8) * 2048 + kt * 64 + gc8 * 8]);
  }
}

__global__ __launch_bounds__(256, 4) void attn(
    const u16* __restrict__ Qh, const u16* __restrict__ Kh,
    const u16* __restrict__ Vt, const u64* __restrict__ mbits,
    u16* __restrict__ Zc) {
  __shared__ alignas(16) u16 sK[2][64 * 64];   // [perm key c][d], chunk swz ^(c&7)
  __shared__ alignas(16) u16 sV[2][64 * 64];   // [d][key],      chunk swz ^(d&7)
  const int tid = threadIdx.x, wave = tid >> 6, lane = tid & 63;
  const int quad = lane >> 4, l15 = lane & 15;
  // XCD-bijective swizzle: 1024 blocks; XCD x gets bh range [8x,8x+8), with
  // the 16 qt-blocks of each bh temporally adjacent (L2 locality).
  const int id = blockIdx.y * 16 + blockIdx.x;           // 0..1023
  const int id2 = (id & 7) * 128 + (id >> 3);
  const int bh = id2 >> 4, qt = id2 & 15;
  const int b = bh >> 4, h = bh & 15;
  const int q0 = qt * 128 + wave * 32;
  const int lr8 = lane >> 3, gc8 = (lane & 7) ^ lr8;

  bf16x8 qa[2][2];
#pragma unroll
  for (int g = 0; g < 2; g++)
#pragma unroll
    for (int kc = 0; kc < 2; kc++)
      qa[g][kc] = *(const bf16x8*)&Qh[(bh * 2048 + q0 + g * 16 + l15) * 64 +
                                      kc * 32 + quad * 8];

  // ---- prologue: full-mask check for this wave's 32 rows (all 2048 keys) ----
  const u64* mrow = mbits + (long long)(b * 2048 + q0) * 32;
  u64 am = ~0ull;
#pragma unroll
  for (int i = 0; i < 16; i++) am &= mrow[lane * 16 + i];
  const bool allfull = __all(am == ~0ull);

  f32x4 oacc[2][4];
#pragma unroll
  for (int g = 0; g < 2; g++)
#pragma unroll
    for (int j = 0; j < 4; j++) oacc[g][j] = (f32x4){0.f, 0.f, 0.f, 0.f};
  float lv[2] = {0.f, 0.f};

  // prime buffer 0 with tile 0
  stage_tile(&sK[0][0], &sV[0][0], Kh, Vt, bh, 0, wave, lr8, gc8);
  const f32x4 z4 = (f32x4){0.f, 0.f, 0.f, 0.f};

  for (int kt = 0; kt < 32; kt++) {
    const int cur = kt & 1;
    __syncthreads();   // tile kt staged (vmcnt drained); buf cur^1 free to refill
    if (kt < 31)
      stage_tile(&sK[cur ^ 1][0], &sV[cur ^ 1][0], Kh, Vt, bh, kt + 1,
                 wave, lr8, gc8);   // overlaps with this tile's compute

    // ---- S^T = K Q^T: 8 ds_read_b128 then 16 MFMA (swapped operands) ----
    bf16x8 kF[2][4];
#pragma unroll
    for (int kc = 0; kc < 2; kc++)
#pragma unroll
      for (int j = 0; j < 4; j++)
        kF[kc][j] = *(const bf16x8*)&sK[cur][(16 * j + l15) * 64 +
                                            (((kc * 4 + quad) ^ (l15 & 7)) * 8)];
    f32x4 sacc[2][4];
    __builtin_amdgcn_s_setprio(1);
#pragma unroll
    for (int j = 0; j < 4; j++)
#pragma unroll
      for (int g = 0; g < 2; g++) sacc[g][j] = mfma16(kF[0][j], qa[g][0], z4);
#pragma unroll
    for (int j = 0; j < 4; j++)
#pragma unroll
      for (int g = 0; g < 2; g++)
        sacc[g][j] = mfma16(kF[1][j], qa[g][1], sacc[g][j]);
    __builtin_amdgcn_s_setprio(0);

    // ---- p = exp2(s), packed straight into the PV A-fragment ----
    // sacc[g][j][r] = S[q-row g*16+l15][key 32*(j>>1) + 8*quad + 4*(j&1) + r]
    // pa[g][kc][e]  = P[q-row g*16+l15][key 32*kc + 8*quad + e]
    bf16x8 pa[2][2];
    if (allfull) {
#pragma unroll
      for (int g = 0; g < 2; g++) {
        float ls = 0.f;
#pragma unroll
        for (int kc = 0; kc < 2; kc++) {
          bf16x8 pk;
#pragma unroll
          for (int e = 0; e < 8; e++) {
            float p = __builtin_amdgcn_exp2f(sacc[g][2 * kc + (e >> 2)][e & 3]);
            ls += p;
            pk[e] = (__bf16)p;
          }
          pa[g][kc] = pk;
        }
        lv[g] += ls;
      }
    } else {
#pragma unroll
      for (int g = 0; g < 2; g++) {
        u64 w = mbits[(long long)(b * 2048 + q0 + g * 16 + l15) * 32 + kt];
        float ls = 0.f;
#pragma unroll
        for (int kc = 0; kc < 2; kc++) {
          bf16x8 pk;
#pragma unroll
          for (int e = 0; e < 8; e++) {
            float p = __builtin_amdgcn_exp2f(sacc[g][2 * kc + (e >> 2)][e & 3]);
            p = ((w >> (32 * kc + 8 * quad + e)) & 1ull) ? p : 0.f;
            ls += p;
            pk[e] = (__bf16)p;
          }
          pa[g][kc] = pk;
        }
        lv[g] += ls;
      }
    }

    // ---- O += P V: 8 vF reads + 16 MFMA (A-operand from registers) ----
    bf16x8 vF[2][4];
#pragma unroll
    for (int kc = 0; kc < 2; kc++)
#pragma unroll
      for (int j = 0; j < 4; j++)
        vF[kc][j] = *(const bf16x8*)&sV[cur][(16 * j + l15) * 64 +
                                             (((kc * 4 + quad) ^ (l15 & 7)) * 8)];
    __builtin_amdgcn_s_setprio(1);
#pragma unroll
    for (int kc = 0; kc < 2; kc++)
#pragma unroll
      for (int g = 0; g < 2; g++)
#pragma unroll
        for (int j = 0; j < 4; j++)
          oacc[g][j] = mfma16(pa[g][kc], vF[kc][j], oacc[g][j]);
    __builtin_amdgcn_s_setprio(0);
  }

  // ---- epilogue: row-sums via cross-quad reduce, then scale + store ----
#pragma unroll
  for (int g = 0; g < 2; g++) {
    float s = lv[g];
    s += __shfl_xor(s, 16);
    s += __shfl_xor(s, 32);       // s = full row-sum for q-row g*16+l15
    float inv[4];
#pragma unroll
    for (int r = 0; r < 4; r++)
      inv[r] = 1.f / __shfl(s, quad * 4 + r);   // row-sum for oacc row quad*4+r
#pragma unroll
    for (int j = 0; j < 4; j++)
#pragma unroll
      for (int r = 0; r < 4; r++) {
        int t = q0 + g * 16 + quad * 4 + r;
        Zc[(b * 2048 + t) * 1024 + h * 64 + 16 * j + l15] =
            f2bf(oacc[g][j][r] * inv[r]);
      }
  }
}

// ---------------------------------------------------------------------------
extern "C" void kernel_launch(void* const* d_in, const int* in_sizes, int n_in,
                              void* d_out, int out_size, void* d_ws, size_t ws_size,
                              hipStream_t stream) {
  (void)in_sizes; (void)n_in; (void)out_size; (void)ws_size;
  const float* q    = (const float*)d_in[0];
  const float* k    = (const float*)d_in[1];
  const float* v    = (const float*)d_in[2];
  const int*   mask = (const int*)d_in[3];
  const float* Wq   = (const float*)d_in[4];
  const float* Wk   = (const float*)d_in[5];
  const float* Wv   = (const float*)d_in[6];
  const float* Wo   = (const float*)d_in[7];
  const float* bo   = (const float*)d_in[8];
  float* out = (float*)d_out;

  u16* Xbf = (u16*)d_ws;             // 3 * NX
  u16* Wbf = Xbf + 3LL * NX;         // 4 * NW
  u16* Qh  = Wbf + 4LL * NW;         // [B,H,T,64]  (pre-scaled by log2e/8)
  u16* Kh  = Qh + (long long)NX;     // [B,H,T,64]
  u16* Vt  = Kh + (long long)NX;     // [B,H,64,T]
  u16* Zc  = Vt + (long long)NX;     // [B*T, 1024]
  u64* Mb  = (u64*)(Zc + (long long)NX);  // [B*T][32] packed mask bits (2 MB)

  cast_all<<<16384, 256, 0, stream>>>(q, k, v, Wq, Wk, Wv, Wo, Xbf, Wbf, mask, Mb);
  gemm128<0><<<dim3(8, 64, 3), 256, 0, stream>>>(Xbf, Wbf, Qh, Kh, Vt, nullptr, nullptr);
  attn<<<dim3(16, 64), 256, 0, stream>>>(Qh, Kh, Vt, Mb, Zc);
  gemm128<1><<<dim3(8, 64), 256, 0, stream>>>(Zc, Wbf + 3LL * NW, nullptr, nullptr, nullptr,
                                              bo, out);
}

// Round 7
// 374.133 us; speedup vs baseline: 1.0691x; 1.0427x over previous
//
#include <hip/hip_runtime.h>

typedef __bf16 bf16x8 __attribute__((ext_vector_type(8)));
typedef __bf16 bf16x4 __attribute__((ext_vector_type(4)));
typedef float f32x4 __attribute__((ext_vector_type(4)));
typedef unsigned short u16;
typedef unsigned long long u64;

#define NX 8388608   // 8192*1024 elements (one [B*T, D] matrix)
#define NW 1048576   // 1024*1024 elements (one weight matrix)

__device__ __forceinline__ u16 f2bf(float f) {
  union { float f; unsigned u; } c; c.f = f;
  unsigned u = c.u;
  u += 0x7fffu + ((u >> 16) & 1u);   // round-to-nearest-even
  return (u16)(u >> 16);
}

__device__ __forceinline__ f32x4 mfma16(bf16x8 a, bf16x8 b, f32x4 c) {
  return __builtin_amdgcn_mfma_f32_16x16x32_bf16(a, b, c, 0, 0, 0);
}

// async global->LDS, 16 B per lane; LDS dest = uniform base + lane*16
__device__ __forceinline__ void gld16(void* lds, const void* g) {
  __builtin_amdgcn_global_load_lds(
      (const __attribute__((address_space(1))) unsigned int*)g,
      (__attribute__((address_space(3))) unsigned int*)lds, 16, 0, 0);
}

// ---------------------------------------------------------------------------
// Kernel 1: cast fp32 -> bf16 for q,k,v and the 4 weight matrices, with the
// mask bit-pack fused in (blocks >= 14336 do mask rows; one launch saved).
// ---------------------------------------------------------------------------
__global__ __launch_bounds__(256) void cast_all(
    const float* __restrict__ q, const float* __restrict__ k,
    const float* __restrict__ v, const float* __restrict__ wq,
    const float* __restrict__ wk, const float* __restrict__ wv,
    const float* __restrict__ wo, u16* __restrict__ xbf, u16* __restrict__ wbf,
    const int* __restrict__ mask, u64* __restrict__ bits) {
  if (blockIdx.x >= 14336) {
    // ---- mask pack: [B,T,T] int32 -> [B*T][32] u64 (bit=1: keep) ----
    const int row = (blockIdx.x - 14336) * 4 + (threadIdx.x >> 6);  // 0..8191
    const int lane = threadIdx.x & 63;
    const int* mrow = mask + (long long)row * 2048;
#pragma unroll
    for (int it = 0; it < 32; it++) {
      u64 w = __ballot(mrow[it * 64 + lane] != 0);
      if (lane == 0) bits[row * 32 + it] = w;
    }
    return;
  }
  long long i = ((long long)blockIdx.x * 256 + threadIdx.x) * 8;
  const float* src; u16* dst; long long off;
  if (i < (long long)NX)            { src = q; dst = xbf;            off = i; }
  else if (i < 2LL * NX)            { src = k; dst = xbf + NX;       off = i - NX; }
  else if (i < 3LL * NX)            { src = v; dst = xbf + 2LL * NX; off = i - 2LL * NX; }
  else {
    long long j = i - 3LL * NX;
    int w = (int)(j / NW); off = j - (long long)w * NW;
    src = (w == 0) ? wq : (w == 1) ? wk : (w == 2) ? wv : wo;
    dst = wbf + (long long)w * NW;
  }
  float4 a = *(const float4*)(src + off);
  float4 b = *(const float4*)(src + off + 4);
  u16 o[8] = {f2bf(a.x), f2bf(a.y), f2bf(a.z), f2bf(a.w),
              f2bf(b.x), f2bf(b.y), f2bf(b.z), f2bf(b.w)};
  *(uint4*)(dst + off) = *(const uint4*)o;
}

// ---------------------------------------------------------------------------
// Kernel 2/4: 128x128x(K=1024) NT-GEMM, counted-vmcnt double-buffered K-loop
// (R6 form, verified). Stage tile ks+1 into buf^1 BEFORE computing tile ks;
// wait s_waitcnt vmcnt(8) (tile ks's loads, issued one K-step earlier) + raw
// s_barrier (no drain). sched_barrier(0) pins compute between the barriers.
// LDS 64 KB (2 x 32 KB stage) -> 2 blocks/CU.
// XCD-bijective block swizzle: XCD x owns m-panels [8x,8x+8) x all n (per z).
// MODE 0: QKV projection; Q (pre-scaled by log2e/8), K -> [B,H,T,64];
//         V -> [B,H,64,T]. Epilogues via LDS transpose -> 128 B/lane stores.
// MODE 1: out projection -> fp32 [B*T,1024] + bias (two 32-col LDS passes).
// ---------------------------------------------------------------------------
__device__ __forceinline__ void gstage(
    u16* sAb, u16* sBb, const u16* __restrict__ A, const u16* __restrict__ W,
    int m0, int n0, int k0, int wave, int lr, int gc) {
#pragma unroll
  for (int t = 0; t < 4; t++) {
    const int rb = wave * 32 + t * 8;          // wave-uniform row base
    gld16(&sAb[rb * 64], &A[(m0 + rb + lr) * 1024 + k0 + gc * 8]);
    gld16(&sBb[rb * 64], &W[(n0 + rb + lr) * 1024 + k0 + gc * 8]);
  }
}

template <int MODE>
__global__ __launch_bounds__(256, 2) void gemm128(
    const u16* __restrict__ Abase, const u16* __restrict__ Wbase,
    u16* __restrict__ oq, u16* __restrict__ ok, u16* __restrict__ ovt,
    const float* __restrict__ bias, float* __restrict__ of) {
  __shared__ alignas(16) u16 smem[2][2][128 * 64];   // [buf][A/B][tile]
  const u16* A = Abase;
  const u16* W = Wbase;
  if (MODE == 0) { A += (long long)blockIdx.z * NX; W += (long long)blockIdx.z * NW; }
  const int tid = threadIdx.x, wave = tid >> 6, lane = tid & 63;
  const int quad = lane >> 4, l15 = lane & 15;
  // XCD-bijective swizzle over the 512 xy-blocks (x fastest in dispatch order;
  // 512 % 8 == 0 so the mapping holds identically for every z-slice).
  const int id = blockIdx.y * 8 + blockIdx.x;            // 0..511
  const int id2 = (id & 7) * 64 + (id >> 3);             // XCD-contiguous
  const int m0 = (id2 >> 3) * 128, n0 = (id2 & 7) * 128;
  const int wm = (wave & 1) * 64, wn = (wave >> 1) * 64;
  const int lr = lane >> 3;            // 0..7: row within 8-row staging group
  const int gc = (lane & 7) ^ lr;      // global 16B-chunk index for this lane
  f32x4 acc[4][4];
#pragma unroll
  for (int i = 0; i < 4; i++)
#pragma unroll
    for (int j = 0; j < 4; j++) acc[i][j] = (f32x4){0.f, 0.f, 0.f, 0.f};

  // prime buffer 0 with K-tile 0
  gstage(smem[0][0], smem[0][1], A, W, m0, n0, 0, wave, lr, gc);
  int buf = 0;
  for (int ks = 0; ks < 16; ks++) {
    if (ks < 15) {
      // prefetch next K-tile into the other buffer (8 loads in flight across
      // this tile's compute)
      gstage(smem[buf ^ 1][0], smem[buf ^ 1][1], A, W, m0, n0, (ks + 1) * 64,
             wave, lr, gc);
      asm volatile("s_waitcnt vmcnt(8)" ::: "memory");   // tile ks staged
    } else {
      asm volatile("s_waitcnt vmcnt(0)" ::: "memory");   // last tile staged
    }
    __builtin_amdgcn_s_barrier();          // all waves: tile ks visible
    __builtin_amdgcn_sched_barrier(0);     // no ds_read hoists above this
    const u16* cA = smem[buf][0];
    const u16* cB = smem[buf][1];
#pragma unroll
    for (int kc = 0; kc < 2; kc++) {
      bf16x8 aF[4], bF[4];
#pragma unroll
      for (int i = 0; i < 4; i++)
        aF[i] = *(const bf16x8*)&cA[(wm + 16 * i + l15) * 64 +
                                    (((kc * 4 + quad) ^ (l15 & 7)) * 8)];
#pragma unroll
      for (int j = 0; j < 4; j++)
        bF[j] = *(const bf16x8*)&cB[(wn + 16 * j + l15) * 64 +
                                    (((kc * 4 + quad) ^ (l15 & 7)) * 8)];
#pragma unroll
      for (int i = 0; i < 4; i++)
#pragma unroll
        for (int j = 0; j < 4; j++) acc[i][j] = mfma16(aF[i], bF[j], acc[i][j]);
    }
    __builtin_amdgcn_sched_barrier(0);     // no compute sinks below this
    __builtin_amdgcn_s_barrier();          // all waves done reading buf
    buf ^= 1;
  }

  // Epilogue. C/D layout: row = quad*4 + reg, col = l15 (m89/m91 verified).
  if (MODE == 0) {
    const int z = blockIdx.z;
    __syncthreads();                  // all waves past final compute barrier
    if (z < 2) {
      // Q/K: stage this wave's 64x64 chunk [t][d] in LDS (chunk-swizzled),
      // read back one 128-B row per lane -> fully coalesced stores.
      const float qscale = (z == 0) ? 0.18033688f : 1.0f;  // log2(e)/8 folded
      u16* dst = (z == 0) ? oq : ok;
      u16* sT = &smem[0][0][0] + wave * 4096;  // 64x64 u16 = 8 KB per wave
#pragma unroll
      for (int i = 0; i < 4; i++)
#pragma unroll
        for (int j = 0; j < 4; j++)
#pragma unroll
          for (int r = 0; r < 4; r++) {
            int m = 16 * i + quad * 4 + r;   // local t (0..63)
            int d = 16 * j + l15;            // local d (0..63)
            sT[m * 64 + (((d >> 3) ^ (m & 7)) * 8) + (d & 7)] =
                f2bf(acc[i][j][r] * qscale);
          }
      // wave-local read-back (in-order DS pipe; no barrier needed)
      const int bq = m0 >> 11, t0w = (m0 + wm) & 2047;
      const int hq = (n0 + wn) >> 6;   // d-range is 64-aligned
      u16* dq = dst + ((long long)((bq << 4) + hq) * 2048 + t0w + lane) * 64;
#pragma unroll
      for (int c = 0; c < 8; c++) {
        uint4 val = *(const uint4*)&sT[lane * 64 + ((c ^ (lane & 7)) * 8)];
        *(uint4*)(dq + c * 8) = val;
      }
    } else {
      // V^T: transpose each wave's 64x64 chunk in LDS, store coalesced.
      u16* sT = &smem[0][0][0] + wave * 4096;  // 64x64, chunk-swizzled
#pragma unroll
      for (int i = 0; i < 4; i++)
#pragma unroll
        for (int j = 0; j < 4; j++)
#pragma unroll
          for (int r = 0; r < 4; r++) {
            int m = 16 * i + quad * 4 + r;   // local t (0..63)
            int n = 16 * j + l15;            // local d (0..63)
            sT[n * 64 + (((m >> 3) ^ (n & 7)) * 8) + (m & 7)] = f2bf(acc[i][j][r]);
          }
      // wave-local read-back (in-order DS pipe; no barrier needed)
      const int b = m0 >> 11, t0 = (m0 + wm) & 2047;
      const int h = (n0 + wn) >> 6;   // d-range is 64-aligned
      u16* dst = ovt + ((long long)((b << 4) + h)) * 131072 + lane * 2048 + t0;
#pragma unroll
      for (int c = 0; c < 8; c++) {
        uint4 val = *(const uint4*)&sT[lane * 64 + ((c ^ (lane & 7)) * 8)];
        *(uint4*)(dst + c * 8) = val;
      }
    }
  } else {
    // fp32 out + bias: two 32-col LDS passes (8 KB/wave each), one 128-B
    // contiguous store region per lane per pass.
    float bb[4];
#pragma unroll
    for (int j = 0; j < 4; j++) bb[j] = bias[n0 + wn + 16 * j + l15];
    __syncthreads();                  // all waves past final compute barrier
    float* sW = (float*)&smem[0][0][0] + wave * 2048;   // 64x32 f32 = 8 KB
#pragma unroll
    for (int p = 0; p < 2; p++) {
#pragma unroll
      for (int i = 0; i < 4; i++)
#pragma unroll
        for (int jj = 0; jj < 2; jj++)
#pragma unroll
          for (int r = 0; r < 4; r++) {
            int m = 16 * i + quad * 4 + r;   // local row (0..63)
            int d = 16 * jj + l15;           // local col (0..31)
            sW[m * 32 + (((d >> 2) ^ (m & 7)) * 4) + (d & 3)] =
                acc[i][2 * p + jj][r] + bb[2 * p + jj];
          }
      float* dof = of + (long long)(m0 + wm + lane) * 1024 + n0 + wn + p * 32;
#pragma unroll
      for (int c = 0; c < 8; c++) {
        float4 val = *(const float4*)&sW[lane * 32 + ((c ^ (lane & 7)) * 4)];
        *(float4*)(dof + c * 4) = val;
      }
      // pass 1's ds_writes reuse the region after pass 0's ds_reads:
      // wave-local in-order DS pipe guarantees ordering.
    }
  }
}

// ---------------------------------------------------------------------------
// Kernel 3: flash attention, v5 — counted-vmcnt double-buffer (gemm R6
// pattern applied to attn's K/V loop).
//   Old: __syncthreads() at loop top -> compiler drains vmcnt(0) -> every
//   iteration eats the full latency of the just-issued prefetch. New: issue
//   stage(kt+1) FIRST, then s_waitcnt vmcnt(4) (tile kt's 4 loads, issued a
//   full iteration earlier -> already landed; vmcnt retires in-order so any
//   masked-path mbits loads in between are drained too) + raw s_barrier.
//   sched_barrier(0) fences pin ds_reads between the barriers (rule #18).
//   - Swapped QK^T: sacc = mfma(kF, qa) -> lane (quad,l15) holds q-row l15.
//     K staged with A-frag-aligned key permutation so packed bf16 P IS the
//     PV A-fragment. P never touches LDS.
//   - LDS 32 KB -> 4 blocks/CU. Direct-store epilogue (R3 form).
// ---------------------------------------------------------------------------
__device__ __forceinline__ void stage_tile(
    u16* sKb, u16* sVb, const u16* __restrict__ Kh, const u16* __restrict__ Vt,
    int bh, int kt, int wave, int lr8, int gc8) {
#pragma unroll
  for (int t = 0; t < 2; t++) {
    const int rb = wave * 16 + t * 8;          // wave-uniform row base (8 rows/1KB)
    const int c = rb + lr8;                    // LDS row this lane feeds
    // A-frag-aligned key permutation (see kernel header)
    const int kap = (c & 32) + (((c >> 2) & 3) << 3) + ((c & 16) >> 2) + (c & 3);
    gld16(&sKb[rb * 64], &Kh[(bh * 2048 + kt * 64 + kap) * 64 + gc8 * 8]);
    gld16(&sVb[rb * 64], &Vt[(bh * 64 + rb + lr8) * 2048 + kt * 64 + gc8 * 8]);
  }
}

__global__ __launch_bounds__(256, 4) void attn(
    const u16* __restrict__ Qh, const u16* __restrict__ Kh,
    const u16* __restrict__ Vt, const u64* __restrict__ mbits,
    u16* __restrict__ Zc) {
  __shared__ alignas(16) u16 sK[2][64 * 64];   // [perm key c][d], chunk swz ^(c&7)
  __shared__ alignas(16) u16 sV[2][64 * 64];   // [d][key],      chunk swz ^(d&7)
  const int tid = threadIdx.x, wave = tid >> 6, lane = tid & 63;
  const int quad = lane >> 4, l15 = lane & 15;
  // XCD-bijective swizzle: 1024 blocks; XCD x gets bh range [8x,8x+8), with
  // the 16 qt-blocks of each bh temporally adjacent (L2 locality).
  const int id = blockIdx.y * 16 + blockIdx.x;           // 0..1023
  const int id2 = (id & 7) * 128 + (id >> 3);
  const int bh = id2 >> 4, qt = id2 & 15;
  const int b = bh >> 4, h = bh & 15;
  const int q0 = qt * 128 + wave * 32;
  const int lr8 = lane >> 3, gc8 = (lane & 7) ^ lr8;

  bf16x8 qa[2][2];
#pragma unroll
  for (int g = 0; g < 2; g++)
#pragma unroll
    for (int kc = 0; kc < 2; kc++)
      qa[g][kc] = *(const bf16x8*)&Qh[(bh * 2048 + q0 + g * 16 + l15) * 64 +
                                      kc * 32 + quad * 8];

  // ---- prologue: full-mask check for this wave's 32 rows (all 2048 keys) ----
  const u64* mrow = mbits + (long long)(b * 2048 + q0) * 32;
  u64 am = ~0ull;
#pragma unroll
  for (int i = 0; i < 16; i++) am &= mrow[lane * 16 + i];
  const bool allfull = __all(am == ~0ull);

  f32x4 oacc[2][4];
#pragma unroll
  for (int g = 0; g < 2; g++)
#pragma unroll
    for (int j = 0; j < 4; j++) oacc[g][j] = (f32x4){0.f, 0.f, 0.f, 0.f};
  float lv[2] = {0.f, 0.f};

  // prime buffer 0 with tile 0
  stage_tile(&sK[0][0], &sV[0][0], Kh, Vt, bh, 0, wave, lr8, gc8);
  const f32x4 z4 = (f32x4){0.f, 0.f, 0.f, 0.f};

  for (int kt = 0; kt < 32; kt++) {
    const int cur = kt & 1;
    if (kt < 31) {
      // prefetch next tile into the other buffer (write-after-read safe: buf
      // cur^1 was last read in iter kt-1, sealed by its exit barrier)
      stage_tile(&sK[cur ^ 1][0], &sV[cur ^ 1][0], Kh, Vt, bh, kt + 1,
                 wave, lr8, gc8);
      asm volatile("s_waitcnt vmcnt(4)" ::: "memory");   // tile kt staged
    } else {
      asm volatile("s_waitcnt vmcnt(0)" ::: "memory");   // last tile staged
    }
    __builtin_amdgcn_s_barrier();          // all waves: tile kt visible
    __builtin_amdgcn_sched_barrier(0);     // no ds_read hoists above this

    // ---- S^T = K Q^T: 8 ds_read_b128 then 16 MFMA (swapped operands) ----
    bf16x8 kF[2][4];
#pragma unroll
    for (int kc = 0; kc < 2; kc++)
#pragma unroll
      for (int j = 0; j < 4; j++)
        kF[kc][j] = *(const bf16x8*)&sK[cur][(16 * j + l15) * 64 +
                                            (((kc * 4 + quad) ^ (l15 & 7)) * 8)];
    f32x4 sacc[2][4];
    __builtin_amdgcn_s_setprio(1);
#pragma unroll
    for (int j = 0; j < 4; j++)
#pragma unroll
      for (int g = 0; g < 2; g++) sacc[g][j] = mfma16(kF[0][j], qa[g][0], z4);
#pragma unroll
    for (int j = 0; j < 4; j++)
#pragma unroll
      for (int g = 0; g < 2; g++)
        sacc[g][j] = mfma16(kF[1][j], qa[g][1], sacc[g][j]);
    __builtin_amdgcn_s_setprio(0);

    // ---- p = exp2(s), packed straight into the PV A-fragment ----
    // sacc[g][j][r] = S[q-row g*16+l15][key 32*(j>>1) + 8*quad + 4*(j&1) + r]
    // pa[g][kc][e]  = P[q-row g*16+l15][key 32*kc + 8*quad + e]
    bf16x8 pa[2][2];
    if (allfull) {
#pragma unroll
      for (int g = 0; g < 2; g++) {
        float ls = 0.f;
#pragma unroll
        for (int kc = 0; kc < 2; kc++) {
          bf16x8 pk;
#pragma unroll
          for (int e = 0; e < 8; e++) {
            float p = __builtin_amdgcn_exp2f(sacc[g][2 * kc + (e >> 2)][e & 3]);
            ls += p;
            pk[e] = (__bf16)p;
          }
          pa[g][kc] = pk;
        }
        lv[g] += ls;
      }
    } else {
#pragma unroll
      for (int g = 0; g < 2; g++) {
        u64 w = mbits[(long long)(b * 2048 + q0 + g * 16 + l15) * 32 + kt];
        float ls = 0.f;
#pragma unroll
        for (int kc = 0; kc < 2; kc++) {
          bf16x8 pk;
#pragma unroll
          for (int e = 0; e < 8; e++) {
            float p = __builtin_amdgcn_exp2f(sacc[g][2 * kc + (e >> 2)][e & 3]);
            p = ((w >> (32 * kc + 8 * quad + e)) & 1ull) ? p : 0.f;
            ls += p;
            pk[e] = (__bf16)p;
          }
          pa[g][kc] = pk;
        }
        lv[g] += ls;
      }
    }

    // ---- O += P V: 8 vF reads + 16 MFMA (A-operand from registers) ----
    bf16x8 vF[2][4];
#pragma unroll
    for (int kc = 0; kc < 2; kc++)
#pragma unroll
      for (int j = 0; j < 4; j++)
        vF[kc][j] = *(const bf16x8*)&sV[cur][(16 * j + l15) * 64 +
                                             (((kc * 4 + quad) ^ (l15 & 7)) * 8)];
    __builtin_amdgcn_s_setprio(1);
#pragma unroll
    for (int kc = 0; kc < 2; kc++)
#pragma unroll
      for (int g = 0; g < 2; g++)
#pragma unroll
        for (int j = 0; j < 4; j++)
          oacc[g][j] = mfma16(pa[g][kc], vF[kc][j], oacc[g][j]);
    __builtin_amdgcn_s_setprio(0);
    __builtin_amdgcn_sched_barrier(0);     // no ds_read sinks below this
    __builtin_amdgcn_s_barrier();          // all waves done reading buf cur
  }

  // ---- epilogue: row-sums via cross-quad reduce, then scale + store ----
#pragma unroll
  for (int g = 0; g < 2; g++) {
    float s = lv[g];
    s += __shfl_xor(s, 16);
    s += __shfl_xor(s, 32);       // s = full row-sum for q-row g*16+l15
    float inv[4];
#pragma unroll
    for (int r = 0; r < 4; r++)
      inv[r] = 1.f / __shfl(s, quad * 4 + r);   // row-sum for oacc row quad*4+r
#pragma unroll
    for (int j = 0; j < 4; j++)
#pragma unroll
      for (int r = 0; r < 4; r++) {
        int t = q0 + g * 16 + quad * 4 + r;
        Zc[(b * 2048 + t) * 1024 + h * 64 + 16 * j + l15] =
            f2bf(oacc[g][j][r] * inv[r]);
      }
  }
}

// ---------------------------------------------------------------------------
extern "C" void kernel_launch(void* const* d_in, const int* in_sizes, int n_in,
                              void* d_out, int out_size, void* d_ws, size_t ws_size,
                              hipStream_t stream) {
  (void)in_sizes; (void)n_in; (void)out_size; (void)ws_size;
  const float* q    = (const float*)d_in[0];
  const float* k    = (const float*)d_in[1];
  const float* v    = (const float*)d_in[2];
  const int*   mask = (const int*)d_in[3];
  const float* Wq   = (const float*)d_in[4];
  const float* Wk   = (const float*)d_in[5];
  const float* Wv   = (const float*)d_in[6];
  const float* Wo   = (const float*)d_in[7];
  const float* bo   = (const float*)d_in[8];
  float* out = (float*)d_out;

  u16* Xbf = (u16*)d_ws;             // 3 * NX
  u16* Wbf = Xbf + 3LL * NX;         // 4 * NW
  u16* Qh  = Wbf + 4LL * NW;         // [B,H,T,64]  (pre-scaled by log2e/8)
  u16* Kh  = Qh + (long long)NX;     // [B,H,T,64]
  u16* Vt  = Kh + (long long)NX;     // [B,H,64,T]
  u16* Zc  = Vt + (long long)NX;     // [B*T, 1024]
  u64* Mb  = (u64*)(Zc + (long long)NX);  // [B*T][32] packed mask bits (2 MB)

  cast_all<<<16384, 256, 0, stream>>>(q, k, v, Wq, Wk, Wv, Wo, Xbf, Wbf, mask, Mb);
  gemm128<0><<<dim3(8, 64, 3), 256, 0, stream>>>(Xbf, Wbf, Qh, Kh, Vt, nullptr, nullptr);
  attn<<<dim3(16, 64), 256, 0, stream>>>(Qh, Kh, Vt, Mb, Zc);
  gemm128<1><<<dim3(8, 64), 256, 0, stream>>>(Zc, Wbf + 3LL * NW, nullptr, nullptr, nullptr,
                                              bo, out);
}